// Round 1
// baseline (123.815 us; speedup 1.0000x reference)
//
#include <hip/hip_runtime.h>
#include <math.h>

#define Lr 2048
#define Dr 1024
#define Nr 16
#define Gc 64
#define LC (Lr/Gc)      // 32
#define DN (Dr*Nr)      // 16384
#define GDN (Gc*DN)

__device__ __forceinline__ float softplus_f(float x){
  // logaddexp(x, 0) = max(x,0) + log1p(exp(-|x|))
  return fmaxf(x, 0.0f) + log1pf(expf(-fabsf(x)));
}

// z[l] = dot(xs[l,:], WD[:,0]) + bD
__global__ void k_rowdot(const float* __restrict__ xs, const float* __restrict__ WD,
                         const float* __restrict__ bD, float* __restrict__ z){
  int l = blockIdx.x;
  const float* row = xs + (size_t)l*Dr;
  float s = 0.f;
  for (int d = threadIdx.x; d < Dr; d += 256) s = fmaf(row[d], WD[d], s);
  #pragma unroll
  for (int off = 32; off > 0; off >>= 1) s += __shfl_down(s, off, 64);
  __shared__ float red[4];
  int wid = threadIdx.x >> 6, lane = threadIdx.x & 63;
  if (lane == 0) red[wid] = s;
  __syncthreads();
  if (threadIdx.x == 0) z[l] = red[0] + red[1] + red[2] + red[3] + bD[0];
}

// Phase 1: per-(chunk g, channel d) thread computes chunk aggregates for all N chains.
__global__ void k_phase1(const float* __restrict__ xs, const float* __restrict__ WB,
                         const float* __restrict__ bB,
                         const float* __restrict__ lnA, const float* __restrict__ dparam,
                         const float* __restrict__ z,
                         float* __restrict__ Aagg, float* __restrict__ Bagg){
  int t = blockIdx.x*256 + threadIdx.x;
  int g = t >> 10;          // Dr = 1024
  int d = t & (Dr-1);
  float ad[Nr], p[Nr], q[Nr];
  #pragma unroll
  for (int n=0;n<Nr;n++){
    float a = -expf(lnA[d*Nr+n]);
    ad[n] = a;
    float ia = 1.0f/a;
    p[n] = WB[n]*ia;        // (Abar-1)/logAbar*Delta*Bs = (Abar-1)*(xs^2*WB + xs*bB)/Adiag
    q[n] = bB[n]*ia;
  }
  float dp = dparam[d];
  float Ap[Nr], Bc[Nr];
  #pragma unroll
  for (int n=0;n<Nr;n++){ Ap[n]=1.f; Bc[n]=0.f; }
  int l0 = g*LC;
  for (int i=0;i<LC;i++){
    int l = l0+i;
    float x  = xs[(size_t)l*Dr+d];
    float dl = softplus_f(dp + z[l]);
    float x2 = x*x;
    #pragma unroll
    for (int n=0;n<Nr;n++){
      float la = dl*ad[n];
      float Ab = expf(la);
      float Bx = (Ab-1.f)*fmaf(x2, p[n], x*q[n]);
      Ap[n] *= Ab;
      Bc[n] = fmaf(Ab, Bc[n], Bx);
    }
  }
  float4* A4 = (float4*)(Aagg + (size_t)g*DN + d*Nr);
  float4* B4 = (float4*)(Bagg + (size_t)g*DN + d*Nr);
  #pragma unroll
  for (int n4=0;n4<4;n4++){
    A4[n4] = make_float4(Ap[4*n4],Ap[4*n4+1],Ap[4*n4+2],Ap[4*n4+3]);
    B4[n4] = make_float4(Bc[4*n4],Bc[4*n4+1],Bc[4*n4+2],Bc[4*n4+3]);
  }
}

// Phase 2: sequential scan over chunks, emit carry-in h for each chunk.
__global__ void k_carry(const float* __restrict__ Aagg, const float* __restrict__ Bagg,
                        float* __restrict__ carry){
  int t = blockIdx.x*256 + threadIdx.x; // = d*Nr + n
  float h = 0.f;
  for (int g=0; g<Gc; g++){
    carry[(size_t)g*DN + t] = h;
    h = fmaf(Aagg[(size_t)g*DN + t], h, Bagg[(size_t)g*DN + t]);
  }
}

// Phase 3: recompute elementwise with carry-in, write hs and ys.
__global__ void k_phase3(const float* __restrict__ xs, const float* __restrict__ WB,
                         const float* __restrict__ bB, const float* __restrict__ WC,
                         const float* __restrict__ bC,
                         const float* __restrict__ lnA, const float* __restrict__ dparam,
                         const float* __restrict__ z, const float* __restrict__ carry,
                         float* __restrict__ ys, float* __restrict__ hs){
  int t = blockIdx.x*256 + threadIdx.x;
  int g = t >> 10;
  int d = t & (Dr-1);
  float ad[Nr], p[Nr], q[Nr], wc[Nr], bc[Nr], h[Nr];
  #pragma unroll
  for (int n=0;n<Nr;n++){
    float a = -expf(lnA[d*Nr+n]);
    ad[n]=a; float ia=1.f/a;
    p[n]=WB[n]*ia; q[n]=bB[n]*ia;
    wc[n]=WC[n];   bc[n]=bC[n];
    h[n]=carry[(size_t)g*DN + d*Nr + n];
  }
  float dp = dparam[d];
  int l0 = g*LC;
  for (int i=0;i<LC;i++){
    int l=l0+i;
    float x  = xs[(size_t)l*Dr+d];
    float dl = softplus_f(dp + z[l]);
    float x2 = x*x;
    float y = 0.f;
    #pragma unroll
    for (int n=0;n<Nr;n++){
      float la = dl*ad[n];
      float Ab = expf(la);
      float Bx = (Ab-1.f)*fmaf(x2, p[n], x*q[n]);
      h[n] = fmaf(Ab, h[n], Bx);
      y = fmaf(h[n], fmaf(x, wc[n], bc[n]), y);
    }
    float4* H4 = (float4*)(hs + (size_t)l*DN + d*Nr);
    #pragma unroll
    for (int n4=0;n4<4;n4++)
      H4[n4] = make_float4(h[4*n4],h[4*n4+1],h[4*n4+2],h[4*n4+3]);
    ys[(size_t)l*Dr+d] = y;
  }
}

extern "C" void kernel_launch(void* const* d_in, const int* in_sizes, int n_in,
                              void* d_out, int out_size, void* d_ws, size_t ws_size,
                              hipStream_t stream) {
  const float* xs     = (const float*)d_in[0];
  const float* WB     = (const float*)d_in[1];
  const float* bB     = (const float*)d_in[2];
  const float* WC     = (const float*)d_in[3];
  const float* bC     = (const float*)d_in[4];
  const float* WD     = (const float*)d_in[5];
  const float* bD     = (const float*)d_in[6];
  const float* lnA    = (const float*)d_in[7];
  const float* dparam = (const float*)d_in[8];

  float* ys = (float*)d_out;
  float* hs = ys + (size_t)Lr*Dr;

  float* z     = (float*)d_ws;          // Lr
  float* Aagg  = z + Lr;                // GDN
  float* Bagg  = Aagg + GDN;            // GDN
  float* carry = Bagg + GDN;            // GDN  (total ~12.6 MB)

  k_rowdot<<<Lr, 256, 0, stream>>>(xs, WD, bD, z);
  k_phase1<<<(Gc*Dr)/256, 256, 0, stream>>>(xs, WB, bB, lnA, dparam, z, Aagg, Bagg);
  k_carry<<<DN/256, 256, 0, stream>>>(Aagg, Bagg, carry);
  k_phase3<<<(Gc*Dr)/256, 256, 0, stream>>>(xs, WB, bB, WC, bC, lnA, dparam, z, carry, ys, hs);
}

// Round 2
// 118.997 us; speedup vs baseline: 1.0405x; 1.0405x over previous
//
#include <hip/hip_runtime.h>
#include <math.h>

#define Lr 2048
#define Dr 1024
#define Nr 16
#define Gc 64
#define LC (Lr/Gc)      // 32
#define DN (Dr*Nr)      // 16384
#define GDN (Gc*DN)

__device__ __forceinline__ float softplus_f(float x){
  // logaddexp(x, 0) = max(x,0) + log1p(exp(-|x|))
  return fmaxf(x, 0.0f) + log1pf(expf(-fabsf(x)));
}

// z[l] = dot(xs[l,:], WD[:,0]) + bD
__global__ void k_rowdot(const float* __restrict__ xs, const float* __restrict__ WD,
                         const float* __restrict__ bD, float* __restrict__ z){
  int l = blockIdx.x;
  const float4* row = (const float4*)(xs + (size_t)l*Dr);
  const float4* w4  = (const float4*)WD;
  int i = threadIdx.x;           // Dr/4 == 256 == blockDim
  float4 a = row[i], b = w4[i];
  float s = fmaf(a.x,b.x, fmaf(a.y,b.y, fmaf(a.z,b.z, a.w*b.w)));
  #pragma unroll
  for (int off = 32; off > 0; off >>= 1) s += __shfl_down(s, off, 64);
  __shared__ float red[4];
  int wid = threadIdx.x >> 6, lane = threadIdx.x & 63;
  if (lane == 0) red[wid] = s;
  __syncthreads();
  if (threadIdx.x == 0) z[l] = red[0] + red[1] + red[2] + red[3] + bD[0];
}

// Phase 1: thread per (chunk g, channel d, n-quad n4); 4 chains per thread.
__global__ __launch_bounds__(256) void k_phase1(
    const float* __restrict__ xs, const float* __restrict__ WB,
    const float* __restrict__ bB,
    const float* __restrict__ lnA, const float* __restrict__ dparam,
    const float* __restrict__ z,
    float* __restrict__ Aagg, float* __restrict__ Bagg){
  int t  = blockIdx.x*256 + threadIdx.x;
  int g  = t >> 12;             // Dr*4 = 4096 threads per chunk
  int r  = t & 4095;
  int d  = r >> 2;
  int n4 = r & 3;
  float4 la = *(const float4*)(lnA + d*Nr + n4*4);
  float4 wb = *(const float4*)(WB  + n4*4);
  float4 bb = *(const float4*)(bB  + n4*4);
  float lav[4] = {la.x,la.y,la.z,la.w};
  float wbv[4] = {wb.x,wb.y,wb.z,wb.w};
  float bbv[4] = {bb.x,bb.y,bb.z,bb.w};
  float ad[4], p[4], q[4], Ap[4], Bc[4];
  #pragma unroll
  for (int j=0;j<4;j++){
    float a = -expf(lav[j]); ad[j]=a; float ia = 1.f/a;
    p[j]=wbv[j]*ia; q[j]=bbv[j]*ia; Ap[j]=1.f; Bc[j]=0.f;
  }
  float dp = dparam[d];
  int l0 = g*LC;
  for (int i=0;i<LC;i++){
    int l = l0+i;
    float x  = xs[(size_t)l*Dr + d];
    float dl = softplus_f(dp + z[l]);
    float x2 = x*x;
    #pragma unroll
    for (int j=0;j<4;j++){
      float Ab = expf(dl*ad[j]);
      float Bx = (Ab-1.f)*fmaf(x2, p[j], x*q[j]);
      Ap[j] *= Ab;
      Bc[j] = fmaf(Ab, Bc[j], Bx);
    }
  }
  *(float4*)(Aagg + (size_t)g*DN + d*Nr + n4*4) = make_float4(Ap[0],Ap[1],Ap[2],Ap[3]);
  *(float4*)(Bagg + (size_t)g*DN + d*Nr + n4*4) = make_float4(Bc[0],Bc[1],Bc[2],Bc[3]);
}

// Phase 2: sequential scan over chunks, emit carry-in h for each chunk.
__global__ void k_carry(const float* __restrict__ Aagg, const float* __restrict__ Bagg,
                        float* __restrict__ carry){
  int t = blockIdx.x*256 + threadIdx.x; // = d*Nr + n
  float h = 0.f;
  for (int g=0; g<Gc; g++){
    carry[(size_t)g*DN + t] = h;
    h = fmaf(Aagg[(size_t)g*DN + t], h, Bagg[(size_t)g*DN + t]);
  }
}

// Phase 3: recompute elementwise with carry-in, write hs and ys.
__global__ __launch_bounds__(256) void k_phase3(
    const float* __restrict__ xs, const float* __restrict__ WB,
    const float* __restrict__ bB, const float* __restrict__ WC,
    const float* __restrict__ bC,
    const float* __restrict__ lnA, const float* __restrict__ dparam,
    const float* __restrict__ z, const float* __restrict__ carry,
    float* __restrict__ ys, float* __restrict__ hs){
  int t  = blockIdx.x*256 + threadIdx.x;
  int g  = t >> 12;
  int r  = t & 4095;
  int d  = r >> 2;
  int n4 = r & 3;
  float4 la = *(const float4*)(lnA + d*Nr + n4*4);
  float4 wb = *(const float4*)(WB  + n4*4);
  float4 bb = *(const float4*)(bB  + n4*4);
  float4 wcv= *(const float4*)(WC  + n4*4);
  float4 bcv= *(const float4*)(bC  + n4*4);
  float4 h0 = *(const float4*)(carry + (size_t)g*DN + d*Nr + n4*4);
  float lav[4] = {la.x,la.y,la.z,la.w};
  float wbv[4] = {wb.x,wb.y,wb.z,wb.w};
  float bbv[4] = {bb.x,bb.y,bb.z,bb.w};
  float wc[4]  = {wcv.x,wcv.y,wcv.z,wcv.w};
  float bc[4]  = {bcv.x,bcv.y,bcv.z,bcv.w};
  float h[4]   = {h0.x,h0.y,h0.z,h0.w};
  float ad[4], p[4], q[4];
  #pragma unroll
  for (int j=0;j<4;j++){
    float a = -expf(lav[j]); ad[j]=a; float ia = 1.f/a;
    p[j]=wbv[j]*ia; q[j]=bbv[j]*ia;
  }
  float dp = dparam[d];
  int l0 = g*LC;
  for (int i=0;i<LC;i++){
    int l = l0+i;
    float x  = xs[(size_t)l*Dr + d];
    float dl = softplus_f(dp + z[l]);
    float x2 = x*x;
    float y = 0.f;
    #pragma unroll
    for (int j=0;j<4;j++){
      float Ab = expf(dl*ad[j]);
      float Bx = (Ab-1.f)*fmaf(x2, p[j], x*q[j]);
      h[j] = fmaf(Ab, h[j], Bx);
      y = fmaf(h[j], fmaf(x, wc[j], bc[j]), y);
    }
    *(float4*)(hs + (size_t)l*DN + d*Nr + n4*4) = make_float4(h[0],h[1],h[2],h[3]);
    // reduce y over the 4 n-lanes sharing this d (lanes 4k..4k+3)
    y += __shfl_xor(y, 1, 64);
    y += __shfl_xor(y, 2, 64);
    if (n4 == 0) ys[(size_t)l*Dr + d] = y;
  }
}

extern "C" void kernel_launch(void* const* d_in, const int* in_sizes, int n_in,
                              void* d_out, int out_size, void* d_ws, size_t ws_size,
                              hipStream_t stream) {
  const float* xs     = (const float*)d_in[0];
  const float* WB     = (const float*)d_in[1];
  const float* bB     = (const float*)d_in[2];
  const float* WC     = (const float*)d_in[3];
  const float* bC     = (const float*)d_in[4];
  const float* WD     = (const float*)d_in[5];
  const float* bD     = (const float*)d_in[6];
  const float* lnA    = (const float*)d_in[7];
  const float* dparam = (const float*)d_in[8];

  float* ys = (float*)d_out;
  float* hs = ys + (size_t)Lr*Dr;

  float* z     = (float*)d_ws;          // Lr
  float* Aagg  = z + Lr;                // GDN
  float* Bagg  = Aagg + GDN;            // GDN
  float* carry = Bagg + GDN;            // GDN  (total ~12.6 MB)

  k_rowdot<<<Lr, 256, 0, stream>>>(xs, WD, bD, z);
  k_phase1<<<(Gc*Dr*4)/256, 256, 0, stream>>>(xs, WB, bB, lnA, dparam, z, Aagg, Bagg);
  k_carry<<<DN/256, 256, 0, stream>>>(Aagg, Bagg, carry);
  k_phase3<<<(Gc*Dr*4)/256, 256, 0, stream>>>(xs, WB, bB, WC, bC, lnA, dparam, z, carry, ys, hs);
}

// Round 5
// 60.977 us; speedup vs baseline: 2.0305x; 1.9515x over previous
//
#include <hip/hip_runtime.h>

#define Lr 2048
#define Dr 1024
#define Nr 16
#define Gc 64
#define LC (Lr/Gc)      // 32
#define DN (Dr*Nr)      // 16384
#define GDN (Gc*DN)

#define LOG2E 1.442695041f
#define LN2   0.69314718056f

typedef float f32x4 __attribute__((ext_vector_type(4)));

__device__ __forceinline__ float exp2_hw(float x){ return __builtin_amdgcn_exp2f(x); }
__device__ __forceinline__ float log2_hw(float x){ return __builtin_amdgcn_logf(x); }
__device__ __forceinline__ float exp_hw(float x) { return exp2_hw(x*LOG2E); }

// fast softplus: max(x,0) + ln2*log2(1+exp2(-|x|*log2e))
__device__ __forceinline__ float softplus_fast(float x){
  float t = exp2_hw(-LOG2E*fabsf(x));
  return fmaxf(x, 0.f) + LN2*log2_hw(1.f + t);
}

// z[l] = dot(xs[l,:], WD[:,0]) + bD
__global__ void k_rowdot(const float* __restrict__ xs, const float* __restrict__ WD,
                         const float* __restrict__ bD, float* __restrict__ z){
  int l = blockIdx.x;
  const float4* row = (const float4*)(xs + (size_t)l*Dr);
  const float4* w4  = (const float4*)WD;
  int i = threadIdx.x;           // Dr/4 == 256 == blockDim
  float4 a = row[i], b = w4[i];
  float s = fmaf(a.x,b.x, fmaf(a.y,b.y, fmaf(a.z,b.z, a.w*b.w)));
  #pragma unroll
  for (int off = 32; off > 0; off >>= 1) s += __shfl_down(s, off, 64);
  __shared__ float red[4];
  int wid = threadIdx.x >> 6, lane = threadIdx.x & 63;
  if (lane == 0) red[wid] = s;
  __syncthreads();
  if (threadIdx.x == 0) z[l] = red[0] + red[1] + red[2] + red[3] + bD[0];
}

// Phase 1: thread per (chunk g, channel d, n-quad n4); 4 chains per thread.
__global__ __launch_bounds__(256) void k_phase1(
    const float* __restrict__ xs, const float* __restrict__ WB,
    const float* __restrict__ bB,
    const float* __restrict__ lnA, const float* __restrict__ dparam,
    const float* __restrict__ z,
    float* __restrict__ Aagg, float* __restrict__ Bagg){
  int t  = blockIdx.x*256 + threadIdx.x;
  int g  = t >> 12;             // Dr*4 = 4096 threads per chunk
  int r  = t & 4095;
  int d  = r >> 2;
  int n4 = r & 3;
  float4 la = *(const float4*)(lnA + d*Nr + n4*4);
  float4 wb = *(const float4*)(WB  + n4*4);
  float4 bb = *(const float4*)(bB  + n4*4);
  float lav[4] = {la.x,la.y,la.z,la.w};
  float wbv[4] = {wb.x,wb.y,wb.z,wb.w};
  float bbv[4] = {bb.x,bb.y,bb.z,bb.w};
  float ad2[4], p[4], q[4], Ap[4], Bc[4];
  #pragma unroll
  for (int j=0;j<4;j++){
    float a = -exp_hw(lav[j]);
    ad2[j] = a*LOG2E;                 // Adiag * log2(e) for exp2
    float ia = 1.f/a;
    p[j]=wbv[j]*ia; q[j]=bbv[j]*ia; Ap[j]=1.f; Bc[j]=0.f;
  }
  float dp = dparam[d];
  int l0 = g*LC;
  #pragma unroll 2
  for (int i=0;i<LC;i++){
    int l = l0+i;
    float x  = xs[(size_t)l*Dr + d];
    float dl = softplus_fast(dp + z[l]);
    float x2 = x*x;
    #pragma unroll
    for (int j=0;j<4;j++){
      float Ab = exp2_hw(dl*ad2[j]);
      float Bx = (Ab-1.f)*fmaf(x2, p[j], x*q[j]);
      Ap[j] *= Ab;
      Bc[j] = fmaf(Ab, Bc[j], Bx);
    }
  }
  *(float4*)(Aagg + (size_t)g*DN + d*Nr + n4*4) = make_float4(Ap[0],Ap[1],Ap[2],Ap[3]);
  *(float4*)(Bagg + (size_t)g*DN + d*Nr + n4*4) = make_float4(Bc[0],Bc[1],Bc[2],Bc[3]);
}

// Phase 2: sequential scan over chunks; 256 blocks x 64 threads -> 1 block/CU on all CUs.
__global__ __launch_bounds__(64) void k_carry(
    const float* __restrict__ Aagg, const float* __restrict__ Bagg,
    float* __restrict__ carry){
  int t = blockIdx.x*64 + threadIdx.x; // = d*Nr + n
  float h = 0.f;
  #pragma unroll 8
  for (int g=0; g<Gc; g++){
    carry[(size_t)g*DN + t] = h;
    h = fmaf(Aagg[(size_t)g*DN + t], h, Bagg[(size_t)g*DN + t]);
  }
}

// Phase 3: recompute elementwise with carry-in, write hs and ys (non-temporal).
__global__ __launch_bounds__(256) void k_phase3(
    const float* __restrict__ xs, const float* __restrict__ WB,
    const float* __restrict__ bB, const float* __restrict__ WC,
    const float* __restrict__ bC,
    const float* __restrict__ lnA, const float* __restrict__ dparam,
    const float* __restrict__ z, const float* __restrict__ carry,
    float* __restrict__ ys, float* __restrict__ hs){
  int t  = blockIdx.x*256 + threadIdx.x;
  int g  = t >> 12;
  int r  = t & 4095;
  int d  = r >> 2;
  int n4 = r & 3;
  float4 la = *(const float4*)(lnA + d*Nr + n4*4);
  float4 wb = *(const float4*)(WB  + n4*4);
  float4 bb = *(const float4*)(bB  + n4*4);
  float4 wcv= *(const float4*)(WC  + n4*4);
  float4 bcv= *(const float4*)(bC  + n4*4);
  float4 h0 = *(const float4*)(carry + (size_t)g*DN + d*Nr + n4*4);
  float lav[4] = {la.x,la.y,la.z,la.w};
  float wbv[4] = {wb.x,wb.y,wb.z,wb.w};
  float bbv[4] = {bb.x,bb.y,bb.z,bb.w};
  float wc[4]  = {wcv.x,wcv.y,wcv.z,wcv.w};
  float bc[4]  = {bcv.x,bcv.y,bcv.z,bcv.w};
  float h[4]   = {h0.x,h0.y,h0.z,h0.w};
  float ad2[4], p[4], q[4];
  #pragma unroll
  for (int j=0;j<4;j++){
    float a = -exp_hw(lav[j]);
    ad2[j] = a*LOG2E;
    float ia = 1.f/a;
    p[j]=wbv[j]*ia; q[j]=bbv[j]*ia;
  }
  float dp = dparam[d];
  int l0 = g*LC;
  #pragma unroll 2
  for (int i=0;i<LC;i++){
    int l = l0+i;
    float x  = xs[(size_t)l*Dr + d];
    float dl = softplus_fast(dp + z[l]);
    float x2 = x*x;
    float y = 0.f;
    #pragma unroll
    for (int j=0;j<4;j++){
      float Ab = exp2_hw(dl*ad2[j]);
      float Bx = (Ab-1.f)*fmaf(x2, p[j], x*q[j]);
      h[j] = fmaf(Ab, h[j], Bx);
      y = fmaf(h[j], fmaf(x, wc[j], bc[j]), y);
    }
    f32x4 hv = {h[0],h[1],h[2],h[3]};
    __builtin_nontemporal_store(hv, (f32x4*)(hs + (size_t)l*DN + d*Nr + n4*4));
    // reduce y over the 4 n-lanes sharing this d (lanes 4k..4k+3)
    y += __shfl_xor(y, 1, 64);
    y += __shfl_xor(y, 2, 64);
    if (n4 == 0) __builtin_nontemporal_store(y, &ys[(size_t)l*Dr + d]);
  }
}

extern "C" void kernel_launch(void* const* d_in, const int* in_sizes, int n_in,
                              void* d_out, int out_size, void* d_ws, size_t ws_size,
                              hipStream_t stream) {
  const float* xs     = (const float*)d_in[0];
  const float* WB     = (const float*)d_in[1];
  const float* bB     = (const float*)d_in[2];
  const float* WC     = (const float*)d_in[3];
  const float* bC     = (const float*)d_in[4];
  const float* WD     = (const float*)d_in[5];
  const float* bD     = (const float*)d_in[6];
  const float* lnA    = (const float*)d_in[7];
  const float* dparam = (const float*)d_in[8];

  float* ys = (float*)d_out;
  float* hs = ys + (size_t)Lr*Dr;

  float* z     = (float*)d_ws;          // Lr
  float* Aagg  = z + Lr;                // GDN
  float* Bagg  = Aagg + GDN;            // GDN
  float* carry = Bagg + GDN;            // GDN  (total ~12.6 MB)

  k_rowdot<<<Lr, 256, 0, stream>>>(xs, WD, bD, z);
  k_phase1<<<(Gc*Dr*4)/256, 256, 0, stream>>>(xs, WB, bB, lnA, dparam, z, Aagg, Bagg);
  k_carry<<<DN/64, 64, 0, stream>>>(Aagg, Bagg, carry);
  k_phase3<<<(Gc*Dr*4)/256, 256, 0, stream>>>(xs, WB, bB, WC, bC, lnA, dparam, z, carry, ys, hs);
}